// Round 3
// baseline (718.739 us; speedup 1.0000x reference)
//
#include <hip/hip_runtime.h>

#define NN 50000
#define NE 800000

// ---------------- CSR build ----------------
__global__ __launch_bounds__(256) void zero_cnt_k(int* __restrict__ cnt) {
    int i = blockIdx.x * blockDim.x + threadIdx.x;
    if (i < NN) cnt[i] = 0;
}

__global__ __launch_bounds__(256) void hist_k(const int* __restrict__ dst, int* __restrict__ cnt) {
    int e = blockIdx.x * blockDim.x + threadIdx.x;
    if (e < NE) atomicAdd(&cnt[dst[e]], 1);
}

__global__ __launch_bounds__(256) void dinv_k(const int* __restrict__ cnt, float* __restrict__ dinv) {
    int i = blockIdx.x * blockDim.x + threadIdx.x;
    if (i < NN) dinv[i] = rsqrtf((float)(cnt[i] + 1));  // +1 self loop
}

// single-block exclusive scan of cnt -> rowstart; zeroes cnt for reuse as cursor
#define SCAN_T 256
#define CHUNK ((NN + SCAN_T - 1) / SCAN_T)
__global__ __launch_bounds__(SCAN_T) void scan_k(const int* __restrict__ cnt_in,
                                                 int* __restrict__ cnt_zero,
                                                 int* __restrict__ rowstart) {
    __shared__ int sums[SCAN_T];
    int t = threadIdx.x;
    int base = t * CHUNK;
    int lim = min(base + CHUNK, NN);
    int s = 0;
    for (int i = base; i < lim; i++) s += cnt_in[i];
    sums[t] = s;
    __syncthreads();
    if (t == 0) {
        int run = 0;
        for (int i = 0; i < SCAN_T; i++) { int v = sums[i]; sums[i] = run; run += v; }
    }
    __syncthreads();
    int run = sums[t];
    for (int i = base; i < lim; i++) {
        rowstart[i] = run;
        run += cnt_in[i];
        cnt_zero[i] = 0;
    }
    if (t == SCAN_T - 1) rowstart[NN] = NE;
}

// packs (col, weight) into int2 for a single 8B load per edge in prop
__global__ __launch_bounds__(256) void scatter_k(const int* __restrict__ src,
                                                 const int* __restrict__ dst,
                                                 const int* __restrict__ rowstart,
                                                 int* __restrict__ cursor,
                                                 const float* __restrict__ dinv,
                                                 int2* __restrict__ colw) {
    int e = blockIdx.x * blockDim.x + threadIdx.x;
    if (e >= NE) return;
    int s = src[e], d = dst[e];
    int pos = rowstart[d] + atomicAdd(&cursor[d], 1);
    colw[pos] = make_int2(s, __float_as_int(dinv[s] * dinv[d]));
}

// ---------------- propagation (CSR, dst-stationary) ----------------
// C4 = 1<<LOG2C4 threads per node, one float4 of channels per thread.
// ADDIN:  out = addin[row] + P(h)[row]          (u = y1 + P(y2))
// !ADDIN: out = relu(P(h)[row] + bias)          (h = relu(P(u) + b))
// Self-loop term dinv[d]^2 * h[d] folded into the accumulator init.
template<int LOG2C4, bool ADDIN>
__global__ __launch_bounds__(256) void prop_k(const float4* __restrict__ h4,
                                              const float4* __restrict__ addin4,
                                              const float* __restrict__ bias,
                                              float4* __restrict__ out4,
                                              const int* __restrict__ rowstart,
                                              const int2* __restrict__ colw,
                                              const float* __restrict__ dinv) {
    const int C4 = 1 << LOG2C4;
    unsigned tid = blockIdx.x * blockDim.x + threadIdx.x;
    unsigned node = tid >> LOG2C4;
    if (node >= NN) return;
    unsigned lane = tid & (C4 - 1);
    size_t rowoff = ((size_t)node << LOG2C4) + lane;
    float w0 = dinv[node];
    w0 *= w0;
    float4 hv = h4[rowoff];
    float4 acc;
    if (ADDIN) {
        float4 a = addin4[rowoff];
        acc.x = a.x + w0 * hv.x; acc.y = a.y + w0 * hv.y;
        acc.z = a.z + w0 * hv.z; acc.w = a.w + w0 * hv.w;
    } else {
        float4 b = ((const float4*)bias)[lane];
        acc.x = b.x + w0 * hv.x; acc.y = b.y + w0 * hv.y;
        acc.z = b.z + w0 * hv.z; acc.w = b.w + w0 * hv.w;
    }
    int rs = rowstart[node], re = rowstart[node + 1];
    int i = rs;
    for (; i + 2 <= re; i += 2) {
        int2 cw0 = colw[i];
        int2 cw1 = colw[i + 1];
        float4 v0 = h4[((size_t)cw0.x << LOG2C4) + lane];
        float4 v1 = h4[((size_t)cw1.x << LOG2C4) + lane];
        float w0_ = __int_as_float(cw0.y);
        float w1_ = __int_as_float(cw1.y);
        acc.x += w0_ * v0.x + w1_ * v1.x;
        acc.y += w0_ * v0.y + w1_ * v1.y;
        acc.z += w0_ * v0.z + w1_ * v1.z;
        acc.w += w0_ * v0.w + w1_ * v1.w;
    }
    if (i < re) {
        int2 cw = colw[i];
        float4 v = h4[((size_t)cw.x << LOG2C4) + lane];
        float w = __int_as_float(cw.y);
        acc.x += w * v.x; acc.y += w * v.y; acc.z += w * v.z; acc.w += w * v.w;
    }
    if (!ADDIN) {
        acc.x = fmaxf(acc.x, 0.0f); acc.y = fmaxf(acc.y, 0.0f);
        acc.z = fmaxf(acc.z, 0.0f); acc.w = fmaxf(acc.w, 0.0f);
    }
    out4[rowoff] = acc;
}

// ---------------- register-tiled GEMM: out = A @ [WA | WB] (no bias) ----------------
// Block = 256 threads = 64 (j) x 4 (tn); each thread computes 4 nodes x 1 column.
// JW = width of each weight matrix. JW==64: grid.y selects WA/WB (one per block).
// JW==32: grid.y==1, block spans both matrices. Output split per matrix:
// out[mat * n * JW + node * JW + jw]  (so y1/y2 land in contiguous separate buffers).
template<int K, int JW>
__global__ __launch_bounds__(256) void gemm2w_k(const float* __restrict__ A,
                                                const float* __restrict__ WA,
                                                const float* __restrict__ WB,
                                                float* __restrict__ out, int n) {
    __shared__ float Ws[64 * (K + 4)];  // transposed, padded: Ws[j*(K+4)+k]
    for (int idx = threadIdx.x; idx < 64 * K; idx += 256) {
        int j = idx & 63;
        int k = idx >> 6;
        float v;
        if (JW == 64) {
            const float* W = blockIdx.y ? WB : WA;
            v = W[k * 64 + j];
        } else {
            v = (j < JW) ? WA[k * JW + j] : WB[k * JW + (j - JW)];
        }
        Ws[j * (K + 4) + k] = v;
    }
    __syncthreads();
    int tj = threadIdx.x & 63;
    int tn = threadIdx.x >> 6;
    int node0 = blockIdx.x * 16 + tn * 4;
    const float4* A4 = (const float4*)A;
    float acc[4] = {0.f, 0.f, 0.f, 0.f};
    const float4* wrow = (const float4*)&Ws[tj * (K + 4)];
#pragma unroll
    for (int k4 = 0; k4 < K / 4; k4++) {
        float4 w = wrow[k4];
#pragma unroll
        for (int m = 0; m < 4; m++) {
            float4 a = A4[(size_t)(node0 + m) * (K / 4) + k4];
            acc[m] += a.x * w.x + a.y * w.y + a.z * w.z + a.w * w.w;
        }
    }
    int mat = (JW == 64) ? blockIdx.y : (tj >> 5);
    int jw = (JW == 64) ? tj : (tj & 31);
    float* ob = out + (size_t)mat * n * JW;
#pragma unroll
    for (int m = 0; m < 4; m++) {
        int node = node0 + m;
        if (node < n) ob[(size_t)node * JW + jw] = acc[m];
    }
}

// ---------------- fused projection + coordinate heads ----------------
__global__ __launch_bounds__(256) void heads_k(const float* __restrict__ h2,
                                               const float* __restrict__ Wp1, const float* __restrict__ bp1,
                                               const float* __restrict__ Wp2, const float* __restrict__ bp2,
                                               const float* __restrict__ Wc1, const float* __restrict__ bc1,
                                               const float* __restrict__ Wc2, const float* __restrict__ bc2,
                                               float* __restrict__ coord, float* __restrict__ z, int n) {
    __shared__ float sWp1[32 * 32], sWp2[32 * 32], sWc1[32 * 16], sWc2[16 * 2];
    __shared__ float sbp1[32], sbp2[32], sbc1[16], sbc2[2];
    for (int i = threadIdx.x; i < 1024; i += 256) { sWp1[i] = Wp1[i]; sWp2[i] = Wp2[i]; }
    for (int i = threadIdx.x; i < 512; i += 256) sWc1[i] = Wc1[i];
    if (threadIdx.x < 32) {
        sWc2[threadIdx.x] = Wc2[threadIdx.x];
        sbp1[threadIdx.x] = bp1[threadIdx.x];
        sbp2[threadIdx.x] = bp2[threadIdx.x];
    }
    if (threadIdx.x < 16) sbc1[threadIdx.x] = bc1[threadIdx.x];
    if (threadIdx.x < 2) sbc2[threadIdx.x] = bc2[threadIdx.x];
    __syncthreads();
    int node = blockIdx.x * blockDim.x + threadIdx.x;
    if (node >= n) return;
    float h[32];
#pragma unroll
    for (int k = 0; k < 32; k++) h[k] = h2[(size_t)node * 32 + k];
    float t[32];
#pragma unroll
    for (int j = 0; j < 32; j++) {
        float s = sbp1[j];
#pragma unroll
        for (int k = 0; k < 32; k++) s += h[k] * sWp1[k * 32 + j];
        t[j] = fmaxf(s, 0.0f);
    }
#pragma unroll
    for (int j = 0; j < 32; j++) {
        float s = sbp2[j];
#pragma unroll
        for (int k = 0; k < 32; k++) s += t[k] * sWp2[k * 32 + j];
        z[(size_t)node * 32 + j] = s;
    }
    float tc[16];
#pragma unroll
    for (int j = 0; j < 16; j++) {
        float s = sbc1[j];
#pragma unroll
        for (int k = 0; k < 32; k++) s += h[k] * sWc1[k * 16 + j];
        tc[j] = fmaxf(s, 0.0f);
    }
#pragma unroll
    for (int j = 0; j < 2; j++) {
        float s = sbc2[j];
#pragma unroll
        for (int k = 0; k < 16; k++) s += tc[k] * sWc2[k * 2 + j];
        coord[(size_t)node * 2 + j] = s;
    }
}

extern "C" void kernel_launch(void* const* d_in, const int* in_sizes, int n_in,
                              void* d_out, int out_size, void* d_ws, size_t ws_size,
                              hipStream_t stream) {
    const float* x    = (const float*)d_in[0];
    const int*   ei   = (const int*)d_in[1];
    const int*   src  = ei;
    const int*   dst  = ei + NE;
    const float* W1_1 = (const float*)d_in[2];
    const float* W1_2 = (const float*)d_in[3];
    const float* b1   = (const float*)d_in[4];
    const float* W2_1 = (const float*)d_in[5];
    const float* W2_2 = (const float*)d_in[6];
    const float* b2   = (const float*)d_in[7];
    const float* Wp1  = (const float*)d_in[8];
    const float* bp1  = (const float*)d_in[9];
    const float* Wp2  = (const float*)d_in[10];
    const float* bp2  = (const float*)d_in[11];
    const float* Wc1  = (const float*)d_in[12];
    const float* bc1  = (const float*)d_in[13];
    const float* Wc2  = (const float*)d_in[14];
    const float* bc2  = (const float*)d_in[15];

    // workspace layout (4-byte words; bufY offset padded to 16B alignment)
    float* ws    = (float*)d_ws;
    float* dinv  = ws;                              // NN
    int*   cnt   = (int*)(dinv + NN);               // NN
    int*   rows  = cnt + NN;                        // NN+2 (padded, keeps int2 8B-aligned)
    int2*  colw  = (int2*)(rows + NN + 2);          // NE int2
    float* bufY  = (float*)(colw + NE) + 2;         // +2 words -> 16B aligned; NN*128
    float* bufZ  = bufY + (size_t)NN * 128;         // NN*64

    float* y1 = bufY;                       // NN*64   (then reused as u)
    float* y2 = bufY + (size_t)NN * 64;     // NN*64   (then reused as h1)
    float* u  = y1;                         // u = y1 + P(y2), in-place over y1
    float* h1 = y2;                         // h1 = relu(P(u)+b1), over y2
    float* z1 = bufZ;                       // NN*32   (then reused as u2)
    float* z2 = bufZ + (size_t)NN * 32;     // NN*32   (then reused as h2)
    float* u2 = z1;
    float* h2 = z2;

    float* coord = (float*)d_out;                   // NN*2
    float* z     = (float*)d_out + 2 * NN;          // NN*32

    // 1) CSR build + dinv
    zero_cnt_k<<<(NN + 255) / 256, 256, 0, stream>>>(cnt);
    hist_k<<<(NE + 255) / 256, 256, 0, stream>>>(dst, cnt);
    dinv_k<<<(NN + 255) / 256, 256, 0, stream>>>(cnt, dinv);
    scan_k<<<1, SCAN_T, 0, stream>>>(cnt, cnt, rows);
    scatter_k<<<(NE + 255) / 256, 256, 0, stream>>>(src, dst, rows, cnt, dinv, colw);

    // 2) [y1|y2] = x @ [W1_1|W1_2]   (K=128, two j-blocks of 64)
    gemm2w_k<128, 64><<<dim3(NN / 16, 2), 256, 0, stream>>>(x, W1_1, W1_2, bufY, NN);
    // 3) u = y1 + P(y2)              (C=64)
    prop_k<4, true><<<(NN * 16 + 255) / 256, 256, 0, stream>>>(
        (const float4*)y2, (const float4*)y1, nullptr, (float4*)u, rows, colw, dinv);
    // 4) h1 = relu(P(u) + b1)        (C=64)
    prop_k<4, false><<<(NN * 16 + 255) / 256, 256, 0, stream>>>(
        (const float4*)u, nullptr, b1, (float4*)h1, rows, colw, dinv);
    // 5) [z1|z2] = h1 @ [W2_1|W2_2]  (K=64, one j-block spanning both 32-wide mats)
    gemm2w_k<64, 32><<<dim3(NN / 16, 1), 256, 0, stream>>>(h1, W2_1, W2_2, bufZ, NN);
    // 6) u2 = z1 + P(z2)             (C=32)
    prop_k<3, true><<<(NN * 8 + 255) / 256, 256, 0, stream>>>(
        (const float4*)z2, (const float4*)z1, nullptr, (float4*)u2, rows, colw, dinv);
    // 7) h2 = relu(P(u2) + b2)       (C=32)
    prop_k<3, false><<<(NN * 8 + 255) / 256, 256, 0, stream>>>(
        (const float4*)u2, nullptr, b2, (float4*)h2, rows, colw, dinv);
    // 8) heads
    heads_k<<<(NN + 255) / 256, 256, 0, stream>>>(h2, Wp1, bp1, Wp2, bp2, Wc1, bc1, Wc2, bc2, coord, z, NN);
}

// Round 4
// 480.199 us; speedup vs baseline: 1.4968x; 1.4968x over previous
//
#include <hip/hip_runtime.h>

#define NN 50000
#define NE 800000

// ---------------- CSR build ----------------
__global__ __launch_bounds__(256) void zero_cnt_k(int* __restrict__ cnt) {
    int i = blockIdx.x * blockDim.x + threadIdx.x;
    if (i < NN) cnt[i] = 0;
}

__global__ __launch_bounds__(256) void hist_k(const int* __restrict__ dst, int* __restrict__ cnt) {
    int e = blockIdx.x * blockDim.x + threadIdx.x;
    if (e < NE) atomicAdd(&cnt[dst[e]], 1);
}

__global__ __launch_bounds__(256) void dinv_k(const int* __restrict__ cnt, float* __restrict__ dinv) {
    int i = blockIdx.x * blockDim.x + threadIdx.x;
    if (i < NN) dinv[i] = rsqrtf((float)(cnt[i] + 1));  // +1 self loop
}

// single-block exclusive scan of cnt -> rowstart; zeroes cnt for reuse as cursor
#define SCAN_T 256
#define CHUNK ((NN + SCAN_T - 1) / SCAN_T)
__global__ __launch_bounds__(SCAN_T) void scan_k(const int* __restrict__ cnt_in,
                                                 int* __restrict__ cnt_zero,
                                                 int* __restrict__ rowstart) {
    __shared__ int sums[SCAN_T];
    int t = threadIdx.x;
    int base = t * CHUNK;
    int lim = min(base + CHUNK, NN);
    int s = 0;
    for (int i = base; i < lim; i++) s += cnt_in[i];
    sums[t] = s;
    __syncthreads();
    if (t == 0) {
        int run = 0;
        for (int i = 0; i < SCAN_T; i++) { int v = sums[i]; sums[i] = run; run += v; }
    }
    __syncthreads();
    int run = sums[t];
    for (int i = base; i < lim; i++) {
        rowstart[i] = run;
        run += cnt_in[i];
        cnt_zero[i] = 0;
    }
    if (t == SCAN_T - 1) rowstart[NN] = NE;
}

// packs (col, weight) into int2 for a single 8B load per edge in prop
__global__ __launch_bounds__(256) void scatter_k(const int* __restrict__ src,
                                                 const int* __restrict__ dst,
                                                 const int* __restrict__ rowstart,
                                                 int* __restrict__ cursor,
                                                 const float* __restrict__ dinv,
                                                 int2* __restrict__ colw) {
    int e = blockIdx.x * blockDim.x + threadIdx.x;
    if (e >= NE) return;
    int s = src[e], d = dst[e];
    int pos = rowstart[d] + atomicAdd(&cursor[d], 1);
    colw[pos] = make_int2(s, __float_as_int(dinv[s] * dinv[d]));
}

// ---------------- propagation (CSR, dst-stationary) ----------------
template<int LOG2C4, bool ADDIN>
__global__ __launch_bounds__(256) void prop_k(const float4* __restrict__ h4,
                                              const float4* __restrict__ addin4,
                                              const float* __restrict__ bias,
                                              float4* __restrict__ out4,
                                              const int* __restrict__ rowstart,
                                              const int2* __restrict__ colw,
                                              const float* __restrict__ dinv) {
    const int C4 = 1 << LOG2C4;
    unsigned tid = blockIdx.x * blockDim.x + threadIdx.x;
    unsigned node = tid >> LOG2C4;
    if (node >= NN) return;
    unsigned lane = tid & (C4 - 1);
    size_t rowoff = ((size_t)node << LOG2C4) + lane;
    float w0 = dinv[node];
    w0 *= w0;
    float4 hv = h4[rowoff];
    float4 acc;
    if (ADDIN) {
        float4 a = addin4[rowoff];
        acc.x = a.x + w0 * hv.x; acc.y = a.y + w0 * hv.y;
        acc.z = a.z + w0 * hv.z; acc.w = a.w + w0 * hv.w;
    } else {
        float4 b = ((const float4*)bias)[lane];
        acc.x = b.x + w0 * hv.x; acc.y = b.y + w0 * hv.y;
        acc.z = b.z + w0 * hv.z; acc.w = b.w + w0 * hv.w;
    }
    int rs = rowstart[node], re = rowstart[node + 1];
    int i = rs;
    for (; i + 2 <= re; i += 2) {
        int2 cw0 = colw[i];
        int2 cw1 = colw[i + 1];
        float4 v0 = h4[((size_t)cw0.x << LOG2C4) + lane];
        float4 v1 = h4[((size_t)cw1.x << LOG2C4) + lane];
        float w0_ = __int_as_float(cw0.y);
        float w1_ = __int_as_float(cw1.y);
        acc.x += w0_ * v0.x + w1_ * v1.x;
        acc.y += w0_ * v0.y + w1_ * v1.y;
        acc.z += w0_ * v0.z + w1_ * v1.z;
        acc.w += w0_ * v0.w + w1_ * v1.w;
    }
    if (i < re) {
        int2 cw = colw[i];
        float4 v = h4[((size_t)cw.x << LOG2C4) + lane];
        float w = __int_as_float(cw.y);
        acc.x += w * v.x; acc.y += w * v.y; acc.z += w * v.z; acc.w += w * v.w;
    }
    if (!ADDIN) {
        acc.x = fmaxf(acc.x, 0.0f); acc.y = fmaxf(acc.y, 0.0f);
        acc.z = fmaxf(acc.z, 0.0f); acc.w = fmaxf(acc.w, 0.0f);
    }
    out4[rowoff] = acc;
}

// ---------------- LDS-tiled GEMM: out = A @ [WA | WB] ----------------
// Block 256 = 16(tn) x 16(tj); C-tile 64 nodes x 64 cols; thread tile 4x4.
// A staged natural (stride 68, b128-aligned), W staged k-major (stride 68).
// Per k4-step: 4 b128 A-reads (4 unique addrs/wave -> broadcast) + 4 b128
// W-reads (16 unique, 2-way) + 64 FMAs.
// JW = per-matrix output width. JW==64: blockIdx.y picks WA/WB.
// JW==32: one block spans both matrices (cols 0..31 -> WA, 32..63 -> WB).
// Output: out[mat * n * JW + node * JW + jw].
template<int K, int JW>
__global__ __launch_bounds__(256) void gemm_k(const float* __restrict__ A,
                                              const float* __restrict__ WA,
                                              const float* __restrict__ WB,
                                              float* __restrict__ out, int n) {
    __shared__ float As[64 * 68];
    __shared__ float Ws[64 * 68];
    const int t = threadIdx.x;
    const int tj = t & 15;
    const int tn = t >> 4;
    const int n0 = blockIdx.x * 64;
    const float* W0 = (JW == 64) ? (blockIdx.y ? WB : WA) : WA;
    float acc[4][4] = {};

    for (int kc = 0; kc < K; kc += 64) {
        if (kc) __syncthreads();
        // stage A: 64 nodes x 64 k, natural layout, coalesced float4 loads
        {
            int idx = t;
#pragma unroll
            for (int r = 0; r < 4; r++, idx += 256) {
                int nl = idx >> 4, q = idx & 15;
                int node = n0 + nl; node = node < n ? node : n - 1;
                float4 a = ((const float4*)A)[(size_t)node * (K / 4) + (kc >> 2) + q];
                *(float4*)&As[nl * 68 + q * 4] = a;
            }
        }
        // stage W: 64 k x 64 j, k-major
        {
            int idx = t;
#pragma unroll
            for (int r = 0; r < 4; r++, idx += 256) {
                int kl = idx >> 4, j4 = idx & 15;
                float4 w;
                if (JW == 64) {
                    w = ((const float4*)W0)[(size_t)(kc + kl) * 16 + j4];
                } else {
                    const float* W = (j4 < 8) ? WA : WB;
                    w = ((const float4*)W)[(size_t)(kc + kl) * 8 + (j4 & 7)];
                }
                *(float4*)&Ws[kl * 68 + j4 * 4] = w;
            }
        }
        __syncthreads();

        const float* ap = &As[tn * 4 * 68];
        const float* wp = &Ws[tj * 4];
#pragma unroll 4
        for (int k4 = 0; k4 < 16; k4++) {
            float4 a0 = *(const float4*)&ap[0 * 68 + k4 * 4];
            float4 a1 = *(const float4*)&ap[1 * 68 + k4 * 4];
            float4 a2 = *(const float4*)&ap[2 * 68 + k4 * 4];
            float4 a3 = *(const float4*)&ap[3 * 68 + k4 * 4];
            float4 w0 = *(const float4*)&wp[(k4 * 4 + 0) * 68];
            float4 w1 = *(const float4*)&wp[(k4 * 4 + 1) * 68];
            float4 w2 = *(const float4*)&wp[(k4 * 4 + 2) * 68];
            float4 w3 = *(const float4*)&wp[(k4 * 4 + 3) * 68];
#define FMA_ROW(m, AV)                                                   \
            acc[m][0] += AV.x * w0.x + AV.y * w1.x + AV.z * w2.x + AV.w * w3.x; \
            acc[m][1] += AV.x * w0.y + AV.y * w1.y + AV.z * w2.y + AV.w * w3.y; \
            acc[m][2] += AV.x * w0.z + AV.y * w1.z + AV.z * w2.z + AV.w * w3.z; \
            acc[m][3] += AV.x * w0.w + AV.y * w1.w + AV.z * w2.w + AV.w * w3.w;
            FMA_ROW(0, a0)
            FMA_ROW(1, a1)
            FMA_ROW(2, a2)
            FMA_ROW(3, a3)
#undef FMA_ROW
        }
    }

    int mat = (JW == 64) ? blockIdx.y : (tj >> 3);
    int jw = (JW == 64) ? tj * 4 : (tj & 7) * 4;
    float* ob = out + (size_t)mat * n * JW + jw;
#pragma unroll
    for (int m = 0; m < 4; m++) {
        int node = n0 + tn * 4 + m;
        if (node < n)
            *(float4*)&ob[(size_t)node * JW] =
                make_float4(acc[m][0], acc[m][1], acc[m][2], acc[m][3]);
    }
}

// ---------------- fused projection + coordinate heads ----------------
__global__ __launch_bounds__(256) void heads_k(const float* __restrict__ h2,
                                               const float* __restrict__ Wp1, const float* __restrict__ bp1,
                                               const float* __restrict__ Wp2, const float* __restrict__ bp2,
                                               const float* __restrict__ Wc1, const float* __restrict__ bc1,
                                               const float* __restrict__ Wc2, const float* __restrict__ bc2,
                                               float* __restrict__ coord, float* __restrict__ z, int n) {
    __shared__ float sWp1[32 * 32], sWp2[32 * 32], sWc1[32 * 16], sWc2[16 * 2];
    __shared__ float sbp1[32], sbp2[32], sbc1[16], sbc2[2];
    for (int i = threadIdx.x; i < 1024; i += 256) { sWp1[i] = Wp1[i]; sWp2[i] = Wp2[i]; }
    for (int i = threadIdx.x; i < 512; i += 256) sWc1[i] = Wc1[i];
    if (threadIdx.x < 32) {
        sWc2[threadIdx.x] = Wc2[threadIdx.x];
        sbp1[threadIdx.x] = bp1[threadIdx.x];
        sbp2[threadIdx.x] = bp2[threadIdx.x];
    }
    if (threadIdx.x < 16) sbc1[threadIdx.x] = bc1[threadIdx.x];
    if (threadIdx.x < 2) sbc2[threadIdx.x] = bc2[threadIdx.x];
    __syncthreads();
    int node = blockIdx.x * blockDim.x + threadIdx.x;
    if (node >= n) return;
    float h[32];
#pragma unroll
    for (int k = 0; k < 32; k++) h[k] = h2[(size_t)node * 32 + k];
    float t[32];
#pragma unroll
    for (int j = 0; j < 32; j++) {
        float s = sbp1[j];
#pragma unroll
        for (int k = 0; k < 32; k++) s += h[k] * sWp1[k * 32 + j];
        t[j] = fmaxf(s, 0.0f);
    }
#pragma unroll
    for (int j = 0; j < 32; j++) {
        float s = sbp2[j];
#pragma unroll
        for (int k = 0; k < 32; k++) s += t[k] * sWp2[k * 32 + j];
        z[(size_t)node * 32 + j] = s;
    }
    float tc[16];
#pragma unroll
    for (int j = 0; j < 16; j++) {
        float s = sbc1[j];
#pragma unroll
        for (int k = 0; k < 32; k++) s += h[k] * sWc1[k * 16 + j];
        tc[j] = fmaxf(s, 0.0f);
    }
#pragma unroll
    for (int j = 0; j < 2; j++) {
        float s = sbc2[j];
#pragma unroll
        for (int k = 0; k < 16; k++) s += tc[k] * sWc2[k * 2 + j];
        coord[(size_t)node * 2 + j] = s;
    }
}

extern "C" void kernel_launch(void* const* d_in, const int* in_sizes, int n_in,
                              void* d_out, int out_size, void* d_ws, size_t ws_size,
                              hipStream_t stream) {
    const float* x    = (const float*)d_in[0];
    const int*   ei   = (const int*)d_in[1];
    const int*   src  = ei;
    const int*   dst  = ei + NE;
    const float* W1_1 = (const float*)d_in[2];
    const float* W1_2 = (const float*)d_in[3];
    const float* b1   = (const float*)d_in[4];
    const float* W2_1 = (const float*)d_in[5];
    const float* W2_2 = (const float*)d_in[6];
    const float* b2   = (const float*)d_in[7];
    const float* Wp1  = (const float*)d_in[8];
    const float* bp1  = (const float*)d_in[9];
    const float* Wp2  = (const float*)d_in[10];
    const float* bp2  = (const float*)d_in[11];
    const float* Wc1  = (const float*)d_in[12];
    const float* bc1  = (const float*)d_in[13];
    const float* Wc2  = (const float*)d_in[14];
    const float* bc2  = (const float*)d_in[15];

    // workspace layout (4-byte words; bufY offset padded to 16B alignment)
    float* ws    = (float*)d_ws;
    float* dinv  = ws;                              // NN
    int*   cnt   = (int*)(dinv + NN);               // NN
    int*   rows  = cnt + NN;                        // NN+2 (padded, keeps int2 8B-aligned)
    int2*  colw  = (int2*)(rows + NN + 2);          // NE int2
    float* bufY  = (float*)(colw + NE) + 2;         // +2 words -> 16B aligned; NN*128
    float* bufZ  = bufY + (size_t)NN * 128;         // NN*64

    float* y1 = bufY;                       // NN*64   (then reused as u)
    float* y2 = bufY + (size_t)NN * 64;     // NN*64   (then reused as h1)
    float* u  = y1;
    float* h1 = y2;
    float* z1 = bufZ;                       // NN*32   (then reused as u2)
    float* z2 = bufZ + (size_t)NN * 32;     // NN*32   (then reused as h2)
    float* u2 = z1;
    float* h2 = z2;

    float* coord = (float*)d_out;                   // NN*2
    float* z     = (float*)d_out + 2 * NN;          // NN*32

    // 1) CSR build + dinv
    zero_cnt_k<<<(NN + 255) / 256, 256, 0, stream>>>(cnt);
    hist_k<<<(NE + 255) / 256, 256, 0, stream>>>(dst, cnt);
    dinv_k<<<(NN + 255) / 256, 256, 0, stream>>>(cnt, dinv);
    scan_k<<<1, SCAN_T, 0, stream>>>(cnt, cnt, rows);
    scatter_k<<<(NE + 255) / 256, 256, 0, stream>>>(src, dst, rows, cnt, dinv, colw);

    // 2) [y1|y2] = x @ [W1_1|W1_2]   (K=128, blockIdx.y picks matrix)
    gemm_k<128, 64><<<dim3((NN + 63) / 64, 2), 256, 0, stream>>>(x, W1_1, W1_2, bufY, NN);
    // 3) u = y1 + P(y2)              (C=64)
    prop_k<4, true><<<(NN * 16 + 255) / 256, 256, 0, stream>>>(
        (const float4*)y2, (const float4*)y1, nullptr, (float4*)u, rows, colw, dinv);
    // 4) h1 = relu(P(u) + b1)        (C=64)
    prop_k<4, false><<<(NN * 16 + 255) / 256, 256, 0, stream>>>(
        (const float4*)u, nullptr, b1, (float4*)h1, rows, colw, dinv);
    // 5) [z1|z2] = h1 @ [W2_1|W2_2]  (K=64, one block spans both 32-wide mats)
    gemm_k<64, 32><<<dim3((NN + 63) / 64, 1), 256, 0, stream>>>(h1, W2_1, W2_2, bufZ, NN);
    // 6) u2 = z1 + P(z2)             (C=32)
    prop_k<3, true><<<(NN * 8 + 255) / 256, 256, 0, stream>>>(
        (const float4*)z2, (const float4*)z1, nullptr, (float4*)u2, rows, colw, dinv);
    // 7) h2 = relu(P(u2) + b2)       (C=32)
    prop_k<3, false><<<(NN * 8 + 255) / 256, 256, 0, stream>>>(
        (const float4*)u2, nullptr, b2, (float4*)h2, rows, colw, dinv);
    // 8) heads
    heads_k<<<(NN + 255) / 256, 256, 0, stream>>>(h2, Wp1, bp1, Wp2, bp2, Wc1, bc1, Wc2, bc2, coord, z, NN);
}

// Round 5
// 368.333 us; speedup vs baseline: 1.9513x; 1.3037x over previous
//
#include <hip/hip_runtime.h>

#define NN 50000
#define NE 800000
#define NBLK ((NN + 255) / 256)   // 196 scan blocks

// ---------------- CSR build ----------------
__global__ __launch_bounds__(256) void zero_cnt_k(int* __restrict__ cnt) {
    int i = blockIdx.x * blockDim.x + threadIdx.x;
    if (i < NN) cnt[i] = 0;
}

__global__ __launch_bounds__(256) void hist_k(const int* __restrict__ dst, int* __restrict__ cnt) {
    int e = blockIdx.x * blockDim.x + threadIdx.x;
    if (e < NE) atomicAdd(&cnt[dst[e]], 1);
}

__global__ __launch_bounds__(256) void dinv_k(const int* __restrict__ cnt, float* __restrict__ dinv) {
    int i = blockIdx.x * blockDim.x + threadIdx.x;
    if (i < NN) dinv[i] = rsqrtf((float)(cnt[i] + 1));  // +1 self loop
}

// ---- hierarchical scan: cnt -> rowstart (exclusive), then cnt := 0 ----
// phase 1: per-block sums
__global__ __launch_bounds__(256) void sum_blocks_k(const int* __restrict__ cnt,
                                                    int* __restrict__ bsum) {
    __shared__ int s[256];
    int t = threadIdx.x;
    int i = blockIdx.x * 256 + t;
    s[t] = (i < NN) ? cnt[i] : 0;
    __syncthreads();
    for (int off = 128; off > 0; off >>= 1) {
        if (t < off) s[t] += s[t + off];
        __syncthreads();
    }
    if (t == 0) bsum[blockIdx.x] = s[0];
}

// phase 2: exclusive scan of NBLK block sums (single tiny block), plus tail
__global__ __launch_bounds__(256) void scan_blocks_k(int* __restrict__ bsum,
                                                     int* __restrict__ rowstart) {
    __shared__ int s[256];
    int t = threadIdx.x;
    int v = (t < NBLK) ? bsum[t] : 0;
    s[t] = v;
    __syncthreads();
    for (int off = 1; off < 256; off <<= 1) {
        int x = (t >= off) ? s[t - off] : 0;
        __syncthreads();
        s[t] += x;
        __syncthreads();
    }
    if (t < NBLK) bsum[t] = s[t] - v;  // exclusive
    if (t == 0) rowstart[NN] = NE;
}

// phase 3: per-block exclusive scan + block offset; zero cnt for cursor reuse
__global__ __launch_bounds__(256) void scan_final_k(int* __restrict__ cnt,
                                                    const int* __restrict__ bsum,
                                                    int* __restrict__ rowstart) {
    __shared__ int s[256];
    int t = threadIdx.x;
    int i = blockIdx.x * 256 + t;
    int v = (i < NN) ? cnt[i] : 0;
    s[t] = v;
    __syncthreads();
    for (int off = 1; off < 256; off <<= 1) {
        int x = (t >= off) ? s[t - off] : 0;
        __syncthreads();
        s[t] += x;
        __syncthreads();
    }
    if (i < NN) {
        rowstart[i] = bsum[blockIdx.x] + s[t] - v;  // exclusive
        cnt[i] = 0;
    }
}

// packs (col, weight) into int2 for a single 8B load per edge in prop
__global__ __launch_bounds__(256) void scatter_k(const int* __restrict__ src,
                                                 const int* __restrict__ dst,
                                                 const int* __restrict__ rowstart,
                                                 int* __restrict__ cursor,
                                                 const float* __restrict__ dinv,
                                                 int2* __restrict__ colw) {
    int e = blockIdx.x * blockDim.x + threadIdx.x;
    if (e >= NE) return;
    int s = src[e], d = dst[e];
    int pos = rowstart[d] + atomicAdd(&cursor[d], 1);
    colw[pos] = make_int2(s, __float_as_int(dinv[s] * dinv[d]));
}

// ---------------- propagation (CSR, dst-stationary) ----------------
template<int LOG2C4, bool ADDIN>
__global__ __launch_bounds__(256) void prop_k(const float4* __restrict__ h4,
                                              const float4* __restrict__ addin4,
                                              const float* __restrict__ bias,
                                              float4* __restrict__ out4,
                                              const int* __restrict__ rowstart,
                                              const int2* __restrict__ colw,
                                              const float* __restrict__ dinv) {
    const int C4 = 1 << LOG2C4;
    unsigned tid = blockIdx.x * blockDim.x + threadIdx.x;
    unsigned node = tid >> LOG2C4;
    if (node >= NN) return;
    unsigned lane = tid & (C4 - 1);
    size_t rowoff = ((size_t)node << LOG2C4) + lane;
    float w0 = dinv[node];
    w0 *= w0;
    float4 hv = h4[rowoff];
    float4 acc;
    if (ADDIN) {
        float4 a = addin4[rowoff];
        acc.x = a.x + w0 * hv.x; acc.y = a.y + w0 * hv.y;
        acc.z = a.z + w0 * hv.z; acc.w = a.w + w0 * hv.w;
    } else {
        float4 b = ((const float4*)bias)[lane];
        acc.x = b.x + w0 * hv.x; acc.y = b.y + w0 * hv.y;
        acc.z = b.z + w0 * hv.z; acc.w = b.w + w0 * hv.w;
    }
    int rs = rowstart[node], re = rowstart[node + 1];
    int i = rs;
    for (; i + 2 <= re; i += 2) {
        int2 cw0 = colw[i];
        int2 cw1 = colw[i + 1];
        float4 v0 = h4[((size_t)cw0.x << LOG2C4) + lane];
        float4 v1 = h4[((size_t)cw1.x << LOG2C4) + lane];
        float w0_ = __int_as_float(cw0.y);
        float w1_ = __int_as_float(cw1.y);
        acc.x += w0_ * v0.x + w1_ * v1.x;
        acc.y += w0_ * v0.y + w1_ * v1.y;
        acc.z += w0_ * v0.z + w1_ * v1.z;
        acc.w += w0_ * v0.w + w1_ * v1.w;
    }
    if (i < re) {
        int2 cw = colw[i];
        float4 v = h4[((size_t)cw.x << LOG2C4) + lane];
        float w = __int_as_float(cw.y);
        acc.x += w * v.x; acc.y += w * v.y; acc.z += w * v.z; acc.w += w * v.w;
    }
    if (!ADDIN) {
        acc.x = fmaxf(acc.x, 0.0f); acc.y = fmaxf(acc.y, 0.0f);
        acc.z = fmaxf(acc.z, 0.0f); acc.w = fmaxf(acc.w, 0.0f);
    }
    out4[rowoff] = acc;
}

// ---------------- LDS-tiled GEMM: out = A @ [WA | WB] ----------------
// Block 256 = 16(tn) x 16(tj); C-tile 64 nodes x 64 cols; thread tile 4x4.
// JW==64: blockIdx.y picks WA/WB. JW==32: one block spans both matrices.
// Output: out[mat * n * JW + node * JW + jw].
template<int K, int JW>
__global__ __launch_bounds__(256) void gemm_k(const float* __restrict__ A,
                                              const float* __restrict__ WA,
                                              const float* __restrict__ WB,
                                              float* __restrict__ out, int n) {
    __shared__ float As[64 * 68];
    __shared__ float Ws[64 * 68];
    const int t = threadIdx.x;
    const int tj = t & 15;
    const int tn = t >> 4;
    const int n0 = blockIdx.x * 64;
    const float* W0 = (JW == 64) ? (blockIdx.y ? WB : WA) : WA;
    float acc[4][4] = {};

    for (int kc = 0; kc < K; kc += 64) {
        if (kc) __syncthreads();
        {
            int idx = t;
#pragma unroll
            for (int r = 0; r < 4; r++, idx += 256) {
                int nl = idx >> 4, q = idx & 15;
                int node = n0 + nl; node = node < n ? node : n - 1;
                float4 a = ((const float4*)A)[(size_t)node * (K / 4) + (kc >> 2) + q];
                *(float4*)&As[nl * 68 + q * 4] = a;
            }
        }
        {
            int idx = t;
#pragma unroll
            for (int r = 0; r < 4; r++, idx += 256) {
                int kl = idx >> 4, j4 = idx & 15;
                float4 w;
                if (JW == 64) {
                    w = ((const float4*)W0)[(size_t)(kc + kl) * 16 + j4];
                } else {
                    const float* W = (j4 < 8) ? WA : WB;
                    w = ((const float4*)W)[(size_t)(kc + kl) * 8 + (j4 & 7)];
                }
                *(float4*)&Ws[kl * 68 + j4 * 4] = w;
            }
        }
        __syncthreads();

        const float* ap = &As[tn * 4 * 68];
        const float* wp = &Ws[tj * 4];
#pragma unroll 4
        for (int k4 = 0; k4 < 16; k4++) {
            float4 a0 = *(const float4*)&ap[0 * 68 + k4 * 4];
            float4 a1 = *(const float4*)&ap[1 * 68 + k4 * 4];
            float4 a2 = *(const float4*)&ap[2 * 68 + k4 * 4];
            float4 a3 = *(const float4*)&ap[3 * 68 + k4 * 4];
            float4 w0 = *(const float4*)&wp[(k4 * 4 + 0) * 68];
            float4 w1 = *(const float4*)&wp[(k4 * 4 + 1) * 68];
            float4 w2 = *(const float4*)&wp[(k4 * 4 + 2) * 68];
            float4 w3 = *(const float4*)&wp[(k4 * 4 + 3) * 68];
#define FMA_ROW(m, AV)                                                   \
            acc[m][0] += AV.x * w0.x + AV.y * w1.x + AV.z * w2.x + AV.w * w3.x; \
            acc[m][1] += AV.x * w0.y + AV.y * w1.y + AV.z * w2.y + AV.w * w3.y; \
            acc[m][2] += AV.x * w0.z + AV.y * w1.z + AV.z * w2.z + AV.w * w3.z; \
            acc[m][3] += AV.x * w0.w + AV.y * w1.w + AV.z * w2.w + AV.w * w3.w;
            FMA_ROW(0, a0)
            FMA_ROW(1, a1)
            FMA_ROW(2, a2)
            FMA_ROW(3, a3)
#undef FMA_ROW
        }
    }

    int mat = (JW == 64) ? blockIdx.y : (tj >> 3);
    int jw = (JW == 64) ? tj * 4 : (tj & 7) * 4;
    float* ob = out + (size_t)mat * n * JW + jw;
#pragma unroll
    for (int m = 0; m < 4; m++) {
        int node = n0 + tn * 4 + m;
        if (node < n)
            *(float4*)&ob[(size_t)node * JW] =
                make_float4(acc[m][0], acc[m][1], acc[m][2], acc[m][3]);
    }
}

// ---------------- fused projection + coordinate heads ----------------
__global__ __launch_bounds__(256) void heads_k(const float* __restrict__ h2,
                                               const float* __restrict__ Wp1, const float* __restrict__ bp1,
                                               const float* __restrict__ Wp2, const float* __restrict__ bp2,
                                               const float* __restrict__ Wc1, const float* __restrict__ bc1,
                                               const float* __restrict__ Wc2, const float* __restrict__ bc2,
                                               float* __restrict__ coord, float* __restrict__ z, int n) {
    __shared__ float sWp1[32 * 32], sWp2[32 * 32], sWc1[32 * 16], sWc2[16 * 2];
    __shared__ float sbp1[32], sbp2[32], sbc1[16], sbc2[2];
    for (int i = threadIdx.x; i < 1024; i += 256) { sWp1[i] = Wp1[i]; sWp2[i] = Wp2[i]; }
    for (int i = threadIdx.x; i < 512; i += 256) sWc1[i] = Wc1[i];
    if (threadIdx.x < 32) {
        sWc2[threadIdx.x] = Wc2[threadIdx.x];
        sbp1[threadIdx.x] = bp1[threadIdx.x];
        sbp2[threadIdx.x] = bp2[threadIdx.x];
    }
    if (threadIdx.x < 16) sbc1[threadIdx.x] = bc1[threadIdx.x];
    if (threadIdx.x < 2) sbc2[threadIdx.x] = bc2[threadIdx.x];
    __syncthreads();
    int node = blockIdx.x * blockDim.x + threadIdx.x;
    if (node >= n) return;
    float h[32];
#pragma unroll
    for (int k = 0; k < 32; k++) h[k] = h2[(size_t)node * 32 + k];
    float t[32];
#pragma unroll
    for (int j = 0; j < 32; j++) {
        float s = sbp1[j];
#pragma unroll
        for (int k = 0; k < 32; k++) s += h[k] * sWp1[k * 32 + j];
        t[j] = fmaxf(s, 0.0f);
    }
#pragma unroll
    for (int j = 0; j < 32; j++) {
        float s = sbp2[j];
#pragma unroll
        for (int k = 0; k < 32; k++) s += t[k] * sWp2[k * 32 + j];
        z[(size_t)node * 32 + j] = s;
    }
    float tc[16];
#pragma unroll
    for (int j = 0; j < 16; j++) {
        float s = sbc1[j];
#pragma unroll
        for (int k = 0; k < 32; k++) s += h[k] * sWc1[k * 16 + j];
        tc[j] = fmaxf(s, 0.0f);
    }
#pragma unroll
    for (int j = 0; j < 2; j++) {
        float s = sbc2[j];
#pragma unroll
        for (int k = 0; k < 16; k++) s += tc[k] * sWc2[k * 2 + j];
        coord[(size_t)node * 2 + j] = s;
    }
}

extern "C" void kernel_launch(void* const* d_in, const int* in_sizes, int n_in,
                              void* d_out, int out_size, void* d_ws, size_t ws_size,
                              hipStream_t stream) {
    const float* x    = (const float*)d_in[0];
    const int*   ei   = (const int*)d_in[1];
    const int*   src  = ei;
    const int*   dst  = ei + NE;
    const float* W1_1 = (const float*)d_in[2];
    const float* W1_2 = (const float*)d_in[3];
    const float* b1   = (const float*)d_in[4];
    const float* W2_1 = (const float*)d_in[5];
    const float* W2_2 = (const float*)d_in[6];
    const float* b2   = (const float*)d_in[7];
    const float* Wp1  = (const float*)d_in[8];
    const float* bp1  = (const float*)d_in[9];
    const float* Wp2  = (const float*)d_in[10];
    const float* bp2  = (const float*)d_in[11];
    const float* Wc1  = (const float*)d_in[12];
    const float* bc1  = (const float*)d_in[13];
    const float* Wc2  = (const float*)d_in[14];
    const float* bc2  = (const float*)d_in[15];

    // workspace layout (4-byte words; bufY offset padded to 16B alignment)
    float* ws    = (float*)d_ws;
    float* dinv  = ws;                              // NN
    int*   cnt   = (int*)(dinv + NN);               // NN
    int*   rows  = cnt + NN;                        // NN+2 (padded, keeps int2 8B-aligned)
    int*   bsum  = rows + NN + 2;                   // NBLK (+pad to even)
    int2*  colw  = (int2*)(bsum + NBLK + (NBLK & 1));  // NE int2
    float* bufY  = (float*)(colw + NE) + 2;         // +2 words -> 16B aligned; NN*128
    float* bufZ  = bufY + (size_t)NN * 128;         // NN*64

    float* y1 = bufY;                       // NN*64   (then reused as u)
    float* y2 = bufY + (size_t)NN * 64;     // NN*64   (then reused as h1)
    float* u  = y1;
    float* h1 = y2;
    float* z1 = bufZ;                       // NN*32   (then reused as u2)
    float* z2 = bufZ + (size_t)NN * 32;     // NN*32   (then reused as h2)
    float* u2 = z1;
    float* h2 = z2;

    float* coord = (float*)d_out;                   // NN*2
    float* z     = (float*)d_out + 2 * NN;          // NN*32

    // 1) CSR build + dinv (hierarchical scan)
    zero_cnt_k<<<(NN + 255) / 256, 256, 0, stream>>>(cnt);
    hist_k<<<(NE + 255) / 256, 256, 0, stream>>>(dst, cnt);
    dinv_k<<<(NN + 255) / 256, 256, 0, stream>>>(cnt, dinv);
    sum_blocks_k<<<NBLK, 256, 0, stream>>>(cnt, bsum);
    scan_blocks_k<<<1, 256, 0, stream>>>(bsum, rows);
    scan_final_k<<<NBLK, 256, 0, stream>>>(cnt, bsum, rows);
    scatter_k<<<(NE + 255) / 256, 256, 0, stream>>>(src, dst, rows, cnt, dinv, colw);

    // 2) [y1|y2] = x @ [W1_1|W1_2]   (K=128, blockIdx.y picks matrix)
    gemm_k<128, 64><<<dim3((NN + 63) / 64, 2), 256, 0, stream>>>(x, W1_1, W1_2, bufY, NN);
    // 3) u = y1 + P(y2)              (C=64)
    prop_k<4, true><<<(NN * 16 + 255) / 256, 256, 0, stream>>>(
        (const float4*)y2, (const float4*)y1, nullptr, (float4*)u, rows, colw, dinv);
    // 4) h1 = relu(P(u) + b1)        (C=64)
    prop_k<4, false><<<(NN * 16 + 255) / 256, 256, 0, stream>>>(
        (const float4*)u, nullptr, b1, (float4*)h1, rows, colw, dinv);
    // 5) [z1|z2] = h1 @ [W2_1|W2_2]  (K=64, one block spans both 32-wide mats)
    gemm_k<64, 32><<<dim3((NN + 63) / 64, 1), 256, 0, stream>>>(h1, W2_1, W2_2, bufZ, NN);
    // 6) u2 = z1 + P(z2)             (C=32)
    prop_k<3, true><<<(NN * 8 + 255) / 256, 256, 0, stream>>>(
        (const float4*)z2, (const float4*)z1, nullptr, (float4*)u2, rows, colw, dinv);
    // 7) h2 = relu(P(u2) + b2)       (C=32)
    prop_k<3, false><<<(NN * 8 + 255) / 256, 256, 0, stream>>>(
        (const float4*)u2, nullptr, b2, (float4*)h2, rows, colw, dinv);
    // 8) heads
    heads_k<<<(NN + 255) / 256, 256, 0, stream>>>(h2, Wp1, bp1, Wp2, bp2, Wc1, bc1, Wc2, bc2, coord, z, NN);
}

// Round 6
// 362.866 us; speedup vs baseline: 1.9807x; 1.0151x over previous
//
#include <hip/hip_runtime.h>

#define NN 50000
#define NE 800000
#define NBLK ((NN + 255) / 256)   // 196 scan blocks

// ---------------- CSR build ----------------
__global__ __launch_bounds__(256) void zero_cnt_k(int* __restrict__ cnt) {
    int i = blockIdx.x * blockDim.x + threadIdx.x;
    if (i < NN) cnt[i] = 0;
}

__global__ __launch_bounds__(256) void hist_k(const int* __restrict__ dst, int* __restrict__ cnt) {
    int e = blockIdx.x * blockDim.x + threadIdx.x;
    if (e < NE) atomicAdd(&cnt[dst[e]], 1);
}

// ---- hierarchical scan: cnt -> rowstart (exclusive), then cnt := 0 ----
// phase 1: per-block sums; also computes dinv = rsqrt(deg+1) (fold, saves a kernel)
__global__ __launch_bounds__(256) void sum_blocks_k(const int* __restrict__ cnt,
                                                    int* __restrict__ bsum,
                                                    float* __restrict__ dinv) {
    __shared__ int s[256];
    int t = threadIdx.x;
    int i = blockIdx.x * 256 + t;
    int v = (i < NN) ? cnt[i] : 0;
    s[t] = v;
    if (i < NN) dinv[i] = rsqrtf((float)(v + 1));  // +1 self loop
    __syncthreads();
    for (int off = 128; off > 0; off >>= 1) {
        if (t < off) s[t] += s[t + off];
        __syncthreads();
    }
    if (t == 0) bsum[blockIdx.x] = s[0];
}

// phase 2: exclusive scan of NBLK block sums (single tiny block), plus tail
__global__ __launch_bounds__(256) void scan_blocks_k(int* __restrict__ bsum,
                                                     int* __restrict__ rowstart) {
    __shared__ int s[256];
    int t = threadIdx.x;
    int v = (t < NBLK) ? bsum[t] : 0;
    s[t] = v;
    __syncthreads();
    for (int off = 1; off < 256; off <<= 1) {
        int x = (t >= off) ? s[t - off] : 0;
        __syncthreads();
        s[t] += x;
        __syncthreads();
    }
    if (t < NBLK) bsum[t] = s[t] - v;  // exclusive
    if (t == 0) rowstart[NN] = NE;
}

// phase 3: per-block exclusive scan + block offset; zero cnt for cursor reuse
__global__ __launch_bounds__(256) void scan_final_k(int* __restrict__ cnt,
                                                    const int* __restrict__ bsum,
                                                    int* __restrict__ rowstart) {
    __shared__ int s[256];
    int t = threadIdx.x;
    int i = blockIdx.x * 256 + t;
    int v = (i < NN) ? cnt[i] : 0;
    s[t] = v;
    __syncthreads();
    for (int off = 1; off < 256; off <<= 1) {
        int x = (t >= off) ? s[t - off] : 0;
        __syncthreads();
        s[t] += x;
        __syncthreads();
    }
    if (i < NN) {
        rowstart[i] = bsum[blockIdx.x] + s[t] - v;  // exclusive
        cnt[i] = 0;
    }
}

// packs (col, weight) into int2 for a single 8B load per edge in prop
__global__ __launch_bounds__(256) void scatter_k(const int* __restrict__ src,
                                                 const int* __restrict__ dst,
                                                 const int* __restrict__ rowstart,
                                                 int* __restrict__ cursor,
                                                 const float* __restrict__ dinv,
                                                 int2* __restrict__ colw) {
    int e = blockIdx.x * blockDim.x + threadIdx.x;
    if (e >= NE) return;
    int s = src[e], d = dst[e];
    int pos = rowstart[d] + atomicAdd(&cursor[d], 1);
    colw[pos] = make_int2(s, __float_as_int(dinv[s] * dinv[d]));
}

// ---------------- propagation (CSR, dst-stationary) ----------------
// 4-wide edge unroll: 4 independent 256B gathers in flight per thread.
template<int LOG2C4, bool ADDIN>
__global__ __launch_bounds__(256) void prop_k(const float4* __restrict__ h4,
                                              const float4* __restrict__ addin4,
                                              const float* __restrict__ bias,
                                              float4* __restrict__ out4,
                                              const int* __restrict__ rowstart,
                                              const int2* __restrict__ colw,
                                              const float* __restrict__ dinv) {
    const int C4 = 1 << LOG2C4;
    unsigned tid = blockIdx.x * blockDim.x + threadIdx.x;
    unsigned node = tid >> LOG2C4;
    if (node >= NN) return;
    unsigned lane = tid & (C4 - 1);
    size_t rowoff = ((size_t)node << LOG2C4) + lane;
    float w0 = dinv[node];
    w0 *= w0;
    float4 hv = h4[rowoff];
    float4 acc;
    if (ADDIN) {
        float4 a = addin4[rowoff];
        acc.x = a.x + w0 * hv.x; acc.y = a.y + w0 * hv.y;
        acc.z = a.z + w0 * hv.z; acc.w = a.w + w0 * hv.w;
    } else {
        float4 b = ((const float4*)bias)[lane];
        acc.x = b.x + w0 * hv.x; acc.y = b.y + w0 * hv.y;
        acc.z = b.z + w0 * hv.z; acc.w = b.w + w0 * hv.w;
    }
    int rs = rowstart[node], re = rowstart[node + 1];
    int i = rs;
    for (; i + 4 <= re; i += 4) {
        int2 cw0 = colw[i];
        int2 cw1 = colw[i + 1];
        int2 cw2 = colw[i + 2];
        int2 cw3 = colw[i + 3];
        float4 v0 = h4[((size_t)cw0.x << LOG2C4) + lane];
        float4 v1 = h4[((size_t)cw1.x << LOG2C4) + lane];
        float4 v2 = h4[((size_t)cw2.x << LOG2C4) + lane];
        float4 v3 = h4[((size_t)cw3.x << LOG2C4) + lane];
        float a0 = __int_as_float(cw0.y);
        float a1 = __int_as_float(cw1.y);
        float a2 = __int_as_float(cw2.y);
        float a3 = __int_as_float(cw3.y);
        acc.x += a0 * v0.x + a1 * v1.x + a2 * v2.x + a3 * v3.x;
        acc.y += a0 * v0.y + a1 * v1.y + a2 * v2.y + a3 * v3.y;
        acc.z += a0 * v0.z + a1 * v1.z + a2 * v2.z + a3 * v3.z;
        acc.w += a0 * v0.w + a1 * v1.w + a2 * v2.w + a3 * v3.w;
    }
    for (; i < re; i++) {
        int2 cw = colw[i];
        float4 v = h4[((size_t)cw.x << LOG2C4) + lane];
        float w = __int_as_float(cw.y);
        acc.x += w * v.x; acc.y += w * v.y; acc.z += w * v.z; acc.w += w * v.w;
    }
    if (!ADDIN) {
        acc.x = fmaxf(acc.x, 0.0f); acc.y = fmaxf(acc.y, 0.0f);
        acc.z = fmaxf(acc.z, 0.0f); acc.w = fmaxf(acc.w, 0.0f);
    }
    out4[rowoff] = acc;
}

// ---------------- layer-1 GEMM: [outA|outB] = A @ [WA|WB], K=128, both mats ----------------
// Block 256 = 16(tn) x 16(tj); C-tile 64 nodes x 128 cols (64 per matrix);
// thread tile 4 nodes x (4+4) cols: quad tj of WA and quad tj of WB.
// W reads at tj*4 stride-68 -> 2-way bank aliasing (free); A reads broadcast.
__global__ __launch_bounds__(256) void gemm1_k(const float* __restrict__ A,
                                               const float* __restrict__ WA,
                                               const float* __restrict__ WB,
                                               float* __restrict__ outA,
                                               float* __restrict__ outB, int n) {
    __shared__ float As[64 * 68];
    __shared__ float W1s[64 * 68];
    __shared__ float W2s[64 * 68];
    const int t = threadIdx.x;
    const int tj = t & 15;
    const int tn = t >> 4;
    const int n0 = blockIdx.x * 64;
    float acc[4][8] = {};

    for (int kc = 0; kc < 128; kc += 64) {
        if (kc) __syncthreads();
        {
            int idx = t;
#pragma unroll
            for (int r = 0; r < 4; r++, idx += 256) {
                int nl = idx >> 4, q = idx & 15;
                int node = n0 + nl; node = node < n ? node : n - 1;
                float4 a = ((const float4*)A)[(size_t)node * 32 + (kc >> 2) + q];
                *(float4*)&As[nl * 68 + q * 4] = a;
            }
        }
        {
            int idx = t;
#pragma unroll
            for (int r = 0; r < 4; r++, idx += 256) {
                int kl = idx >> 4, j4 = idx & 15;
                *(float4*)&W1s[kl * 68 + j4 * 4] = ((const float4*)WA)[(size_t)(kc + kl) * 16 + j4];
                *(float4*)&W2s[kl * 68 + j4 * 4] = ((const float4*)WB)[(size_t)(kc + kl) * 16 + j4];
            }
        }
        __syncthreads();

        const float* ap = &As[tn * 4 * 68];
        const float* w1p = &W1s[tj * 4];
        const float* w2p = &W2s[tj * 4];
#pragma unroll 2
        for (int k4 = 0; k4 < 16; k4++) {
            float4 a0 = *(const float4*)&ap[0 * 68 + k4 * 4];
            float4 a1 = *(const float4*)&ap[1 * 68 + k4 * 4];
            float4 a2 = *(const float4*)&ap[2 * 68 + k4 * 4];
            float4 a3 = *(const float4*)&ap[3 * 68 + k4 * 4];
#pragma unroll
            for (int kk = 0; kk < 4; kk++) {
                float4 w1 = *(const float4*)&w1p[(k4 * 4 + kk) * 68];
                float4 w2 = *(const float4*)&w2p[(k4 * 4 + kk) * 68];
                float av0 = kk == 0 ? a0.x : kk == 1 ? a0.y : kk == 2 ? a0.z : a0.w;
                float av1 = kk == 0 ? a1.x : kk == 1 ? a1.y : kk == 2 ? a1.z : a1.w;
                float av2 = kk == 0 ? a2.x : kk == 1 ? a2.y : kk == 2 ? a2.z : a2.w;
                float av3 = kk == 0 ? a3.x : kk == 1 ? a3.y : kk == 2 ? a3.z : a3.w;
#define FMA8(m, AV)                                                     \
                acc[m][0] += AV * w1.x; acc[m][1] += AV * w1.y;          \
                acc[m][2] += AV * w1.z; acc[m][3] += AV * w1.w;          \
                acc[m][4] += AV * w2.x; acc[m][5] += AV * w2.y;          \
                acc[m][6] += AV * w2.z; acc[m][7] += AV * w2.w;
                FMA8(0, av0)
                FMA8(1, av1)
                FMA8(2, av2)
                FMA8(3, av3)
#undef FMA8
            }
        }
    }

#pragma unroll
    for (int m = 0; m < 4; m++) {
        int node = n0 + tn * 4 + m;
        if (node < n) {
            *(float4*)&outA[(size_t)node * 64 + tj * 4] =
                make_float4(acc[m][0], acc[m][1], acc[m][2], acc[m][3]);
            *(float4*)&outB[(size_t)node * 64 + tj * 4] =
                make_float4(acc[m][4], acc[m][5], acc[m][6], acc[m][7]);
        }
    }
}

// ---------------- layer-2 GEMM: out = A @ [WA|WB], K=64, JW=32 ----------------
template<int K, int JW>
__global__ __launch_bounds__(256) void gemm_k(const float* __restrict__ A,
                                              const float* __restrict__ WA,
                                              const float* __restrict__ WB,
                                              float* __restrict__ out, int n) {
    __shared__ float As[64 * 68];
    __shared__ float Ws[64 * 68];
    const int t = threadIdx.x;
    const int tj = t & 15;
    const int tn = t >> 4;
    const int n0 = blockIdx.x * 64;
    float acc[4][4] = {};

    for (int kc = 0; kc < K; kc += 64) {
        if (kc) __syncthreads();
        {
            int idx = t;
#pragma unroll
            for (int r = 0; r < 4; r++, idx += 256) {
                int nl = idx >> 4, q = idx & 15;
                int node = n0 + nl; node = node < n ? node : n - 1;
                float4 a = ((const float4*)A)[(size_t)node * (K / 4) + (kc >> 2) + q];
                *(float4*)&As[nl * 68 + q * 4] = a;
            }
        }
        {
            int idx = t;
#pragma unroll
            for (int r = 0; r < 4; r++, idx += 256) {
                int kl = idx >> 4, j4 = idx & 15;
                const float* W = (j4 < 8) ? WA : WB;
                float4 w = ((const float4*)W)[(size_t)(kc + kl) * 8 + (j4 & 7)];
                *(float4*)&Ws[kl * 68 + j4 * 4] = w;
            }
        }
        __syncthreads();

        const float* ap = &As[tn * 4 * 68];
        const float* wp = &Ws[tj * 4];
#pragma unroll 4
        for (int k4 = 0; k4 < 16; k4++) {
            float4 a0 = *(const float4*)&ap[0 * 68 + k4 * 4];
            float4 a1 = *(const float4*)&ap[1 * 68 + k4 * 4];
            float4 a2 = *(const float4*)&ap[2 * 68 + k4 * 4];
            float4 a3 = *(const float4*)&ap[3 * 68 + k4 * 4];
            float4 w0 = *(const float4*)&wp[(k4 * 4 + 0) * 68];
            float4 w1 = *(const float4*)&wp[(k4 * 4 + 1) * 68];
            float4 w2 = *(const float4*)&wp[(k4 * 4 + 2) * 68];
            float4 w3 = *(const float4*)&wp[(k4 * 4 + 3) * 68];
#define FMA_ROW(m, AV)                                                   \
            acc[m][0] += AV.x * w0.x + AV.y * w1.x + AV.z * w2.x + AV.w * w3.x; \
            acc[m][1] += AV.x * w0.y + AV.y * w1.y + AV.z * w2.y + AV.w * w3.y; \
            acc[m][2] += AV.x * w0.z + AV.y * w1.z + AV.z * w2.z + AV.w * w3.z; \
            acc[m][3] += AV.x * w0.w + AV.y * w1.w + AV.z * w2.w + AV.w * w3.w;
            FMA_ROW(0, a0)
            FMA_ROW(1, a1)
            FMA_ROW(2, a2)
            FMA_ROW(3, a3)
#undef FMA_ROW
        }
    }

    int mat = tj >> 3;
    int jw = (tj & 7) * 4;
    float* ob = out + (size_t)mat * n * JW + jw;
#pragma unroll
    for (int m = 0; m < 4; m++) {
        int node = n0 + tn * 4 + m;
        if (node < n)
            *(float4*)&ob[(size_t)node * JW] =
                make_float4(acc[m][0], acc[m][1], acc[m][2], acc[m][3]);
    }
}

// ---------------- fused projection + coordinate heads ----------------
__global__ __launch_bounds__(256) void heads_k(const float* __restrict__ h2,
                                               const float* __restrict__ Wp1, const float* __restrict__ bp1,
                                               const float* __restrict__ Wp2, const float* __restrict__ bp2,
                                               const float* __restrict__ Wc1, const float* __restrict__ bc1,
                                               const float* __restrict__ Wc2, const float* __restrict__ bc2,
                                               float* __restrict__ coord, float* __restrict__ z, int n) {
    __shared__ float sWp1[32 * 32], sWp2[32 * 32], sWc1[32 * 16], sWc2[16 * 2];
    __shared__ float sbp1[32], sbp2[32], sbc1[16], sbc2[2];
    for (int i = threadIdx.x; i < 1024; i += 256) { sWp1[i] = Wp1[i]; sWp2[i] = Wp2[i]; }
    for (int i = threadIdx.x; i < 512; i += 256) sWc1[i] = Wc1[i];
    if (threadIdx.x < 32) {
        sWc2[threadIdx.x] = Wc2[threadIdx.x];
        sbp1[threadIdx.x] = bp1[threadIdx.x];
        sbp2[threadIdx.x] = bp2[threadIdx.x];
    }
    if (threadIdx.x < 16) sbc1[threadIdx.x] = bc1[threadIdx.x];
    if (threadIdx.x < 2) sbc2[threadIdx.x] = bc2[threadIdx.x];
    __syncthreads();
    int node = blockIdx.x * blockDim.x + threadIdx.x;
    if (node >= n) return;
    float h[32];
#pragma unroll
    for (int k = 0; k < 32; k++) h[k] = h2[(size_t)node * 32 + k];
    float t[32];
#pragma unroll
    for (int j = 0; j < 32; j++) {
        float s = sbp1[j];
#pragma unroll
        for (int k = 0; k < 32; k++) s += h[k] * sWp1[k * 32 + j];
        t[j] = fmaxf(s, 0.0f);
    }
#pragma unroll
    for (int j = 0; j < 32; j++) {
        float s = sbp2[j];
#pragma unroll
        for (int k = 0; k < 32; k++) s += t[k] * sWp2[k * 32 + j];
        z[(size_t)node * 32 + j] = s;
    }
    float tc[16];
#pragma unroll
    for (int j = 0; j < 16; j++) {
        float s = sbc1[j];
#pragma unroll
        for (int k = 0; k < 32; k++) s += h[k] * sWc1[k * 16 + j];
        tc[j] = fmaxf(s, 0.0f);
    }
#pragma unroll
    for (int j = 0; j < 2; j++) {
        float s = sbc2[j];
#pragma unroll
        for (int k = 0; k < 16; k++) s += tc[k] * sWc2[k * 2 + j];
        coord[(size_t)node * 2 + j] = s;
    }
}

extern "C" void kernel_launch(void* const* d_in, const int* in_sizes, int n_in,
                              void* d_out, int out_size, void* d_ws, size_t ws_size,
                              hipStream_t stream) {
    const float* x    = (const float*)d_in[0];
    const int*   ei   = (const int*)d_in[1];
    const int*   src  = ei;
    const int*   dst  = ei + NE;
    const float* W1_1 = (const float*)d_in[2];
    const float* W1_2 = (const float*)d_in[3];
    const float* b1   = (const float*)d_in[4];
    const float* W2_1 = (const float*)d_in[5];
    const float* W2_2 = (const float*)d_in[6];
    const float* b2   = (const float*)d_in[7];
    const float* Wp1  = (const float*)d_in[8];
    const float* bp1  = (const float*)d_in[9];
    const float* Wp2  = (const float*)d_in[10];
    const float* bp2  = (const float*)d_in[11];
    const float* Wc1  = (const float*)d_in[12];
    const float* bc1  = (const float*)d_in[13];
    const float* Wc2  = (const float*)d_in[14];
    const float* bc2  = (const float*)d_in[15];

    // workspace layout (4-byte words; bufY offset padded to 16B alignment)
    float* ws    = (float*)d_ws;
    float* dinv  = ws;                              // NN
    int*   cnt   = (int*)(dinv + NN);               // NN
    int*   rows  = cnt + NN;                        // NN+2 (padded, keeps int2 8B-aligned)
    int*   bsum  = rows + NN + 2;                   // NBLK (+pad to even)
    int2*  colw  = (int2*)(bsum + NBLK + (NBLK & 1));  // NE int2
    float* bufY  = (float*)(colw + NE) + 2;         // +2 words -> 16B aligned; NN*128
    float* bufZ  = bufY + (size_t)NN * 128;         // NN*64

    float* y1 = bufY;                       // NN*64   (then reused as u)
    float* y2 = bufY + (size_t)NN * 64;     // NN*64   (then reused as h1)
    float* u  = y1;
    float* h1 = y2;
    float* z1 = bufZ;                       // NN*32   (then reused as u2)
    float* z2 = bufZ + (size_t)NN * 32;     // NN*32   (then reused as h2)
    float* u2 = z1;
    float* h2 = z2;

    float* coord = (float*)d_out;                   // NN*2
    float* z     = (float*)d_out + 2 * NN;          // NN*32

    // 1) CSR build + dinv (hierarchical scan; dinv folded into phase 1)
    zero_cnt_k<<<(NN + 255) / 256, 256, 0, stream>>>(cnt);
    hist_k<<<(NE + 255) / 256, 256, 0, stream>>>(dst, cnt);
    sum_blocks_k<<<NBLK, 256, 0, stream>>>(cnt, bsum, dinv);
    scan_blocks_k<<<1, 256, 0, stream>>>(bsum, rows);
    scan_final_k<<<NBLK, 256, 0, stream>>>(cnt, bsum, rows);
    scatter_k<<<(NE + 255) / 256, 256, 0, stream>>>(src, dst, rows, cnt, dinv, colw);

    // 2) [y1|y2] = x @ [W1_1|W1_2]   (K=128, both matrices in one pass)
    gemm1_k<<<(NN + 63) / 64, 256, 0, stream>>>(x, W1_1, W1_2, y1, y2, NN);
    // 3) u = y1 + P(y2)              (C=64)
    prop_k<4, true><<<(NN * 16 + 255) / 256, 256, 0, stream>>>(
        (const float4*)y2, (const float4*)y1, nullptr, (float4*)u, rows, colw, dinv);
    // 4) h1 = relu(P(u) + b1)        (C=64)
    prop_k<4, false><<<(NN * 16 + 255) / 256, 256, 0, stream>>>(
        (const float4*)u, nullptr, b1, (float4*)h1, rows, colw, dinv);
    // 5) [z1|z2] = h1 @ [W2_1|W2_2]  (K=64, one block spans both 32-wide mats)
    gemm_k<64, 32><<<(NN + 63) / 64, 256, 0, stream>>>(h1, W2_1, W2_2, bufZ, NN);
    // 6) u2 = z1 + P(z2)             (C=32)
    prop_k<3, true><<<(NN * 8 + 255) / 256, 256, 0, stream>>>(
        (const float4*)z2, (const float4*)z1, nullptr, (float4*)u2, rows, colw, dinv);
    // 7) h2 = relu(P(u2) + b2)       (C=32)
    prop_k<3, false><<<(NN * 8 + 255) / 256, 256, 0, stream>>>(
        (const float4*)u2, nullptr, b2, (float4*)h2, rows, colw, dinv);
    // 8) heads
    heads_k<<<(NN + 255) / 256, 256, 0, stream>>>(h2, Wp1, bp1, Wp2, bp2, Wc1, bc1, Wc2, bc2, coord, z, NN);
}

// Round 7
// 357.792 us; speedup vs baseline: 2.0088x; 1.0142x over previous
//
#include <hip/hip_runtime.h>

#define NN 50000
#define NE 800000
#define NBLK ((NN + 255) / 256)   // 196 scan blocks

// ---------------- CSR build ----------------
__global__ __launch_bounds__(256) void zero_cnt_k(int* __restrict__ cnt) {
    int i = blockIdx.x * blockDim.x + threadIdx.x;
    if (i < NN) cnt[i] = 0;
}

__global__ __launch_bounds__(256) void hist_k(const int* __restrict__ dst, int* __restrict__ cnt) {
    int e = blockIdx.x * blockDim.x + threadIdx.x;
    if (e < NE) atomicAdd(&cnt[dst[e]], 1);
}

// ---- hierarchical scan: cnt -> rowstart (exclusive), then cnt := 0 ----
// phase 1: per-block sums; also computes dinv = rsqrt(deg+1)
__global__ __launch_bounds__(256) void sum_blocks_k(const int* __restrict__ cnt,
                                                    int* __restrict__ bsum,
                                                    float* __restrict__ dinv) {
    __shared__ int s[256];
    int t = threadIdx.x;
    int i = blockIdx.x * 256 + t;
    int v = (i < NN) ? cnt[i] : 0;
    s[t] = v;
    if (i < NN) dinv[i] = rsqrtf((float)(v + 1));  // +1 self loop
    __syncthreads();
    for (int off = 128; off > 0; off >>= 1) {
        if (t < off) s[t] += s[t + off];
        __syncthreads();
    }
    if (t == 0) bsum[blockIdx.x] = s[0];
}

// phase 2: exclusive scan of NBLK block sums (single tiny block), plus tail
__global__ __launch_bounds__(256) void scan_blocks_k(int* __restrict__ bsum,
                                                     int* __restrict__ rowstart) {
    __shared__ int s[256];
    int t = threadIdx.x;
    int v = (t < NBLK) ? bsum[t] : 0;
    s[t] = v;
    __syncthreads();
    for (int off = 1; off < 256; off <<= 1) {
        int x = (t >= off) ? s[t - off] : 0;
        __syncthreads();
        s[t] += x;
        __syncthreads();
    }
    if (t < NBLK) bsum[t] = s[t] - v;  // exclusive
    if (t == 0) rowstart[NN] = NE;
}

// phase 3: per-block exclusive scan + block offset; zero cnt for cursor reuse
__global__ __launch_bounds__(256) void scan_final_k(int* __restrict__ cnt,
                                                    const int* __restrict__ bsum,
                                                    int* __restrict__ rowstart) {
    __shared__ int s[256];
    int t = threadIdx.x;
    int i = blockIdx.x * 256 + t;
    int v = (i < NN) ? cnt[i] : 0;
    s[t] = v;
    __syncthreads();
    for (int off = 1; off < 256; off <<= 1) {
        int x = (t >= off) ? s[t - off] : 0;
        __syncthreads();
        s[t] += x;
        __syncthreads();
    }
    if (i < NN) {
        rowstart[i] = bsum[blockIdx.x] + s[t] - v;  // exclusive
        cnt[i] = 0;
    }
}

// packs (col, weight) into int2 for a single 8B load per edge in prop
__global__ __launch_bounds__(256) void scatter_k(const int* __restrict__ src,
                                                 const int* __restrict__ dst,
                                                 const int* __restrict__ rowstart,
                                                 int* __restrict__ cursor,
                                                 const float* __restrict__ dinv,
                                                 int2* __restrict__ colw) {
    int e = blockIdx.x * blockDim.x + threadIdx.x;
    if (e >= NE) return;
    int s = src[e], d = dst[e];
    int pos = rowstart[d] + atomicAdd(&cursor[d], 1);
    colw[pos] = make_int2(s, __float_as_int(dinv[s] * dinv[d]));
}

// ---------------- propagation (CSR, dst-stationary) ----------------
template<int LOG2C4, bool ADDIN>
__global__ __launch_bounds__(256) void prop_k(const float4* __restrict__ h4,
                                              const float4* __restrict__ addin4,
                                              const float* __restrict__ bias,
                                              float4* __restrict__ out4,
                                              const int* __restrict__ rowstart,
                                              const int2* __restrict__ colw,
                                              const float* __restrict__ dinv) {
    const int C4 = 1 << LOG2C4;
    unsigned tid = blockIdx.x * blockDim.x + threadIdx.x;
    unsigned node = tid >> LOG2C4;
    if (node >= NN) return;
    unsigned lane = tid & (C4 - 1);
    size_t rowoff = ((size_t)node << LOG2C4) + lane;
    float w0 = dinv[node];
    w0 *= w0;
    float4 hv = h4[rowoff];
    float4 acc;
    if (ADDIN) {
        float4 a = addin4[rowoff];
        acc.x = a.x + w0 * hv.x; acc.y = a.y + w0 * hv.y;
        acc.z = a.z + w0 * hv.z; acc.w = a.w + w0 * hv.w;
    } else {
        float4 b = ((const float4*)bias)[lane];
        acc.x = b.x + w0 * hv.x; acc.y = b.y + w0 * hv.y;
        acc.z = b.z + w0 * hv.z; acc.w = b.w + w0 * hv.w;
    }
    int rs = rowstart[node], re = rowstart[node + 1];
    int i = rs;
    for (; i + 4 <= re; i += 4) {
        int2 cw0 = colw[i];
        int2 cw1 = colw[i + 1];
        int2 cw2 = colw[i + 2];
        int2 cw3 = colw[i + 3];
        float4 v0 = h4[((size_t)cw0.x << LOG2C4) + lane];
        float4 v1 = h4[((size_t)cw1.x << LOG2C4) + lane];
        float4 v2 = h4[((size_t)cw2.x << LOG2C4) + lane];
        float4 v3 = h4[((size_t)cw3.x << LOG2C4) + lane];
        float a0 = __int_as_float(cw0.y);
        float a1 = __int_as_float(cw1.y);
        float a2 = __int_as_float(cw2.y);
        float a3 = __int_as_float(cw3.y);
        acc.x += a0 * v0.x + a1 * v1.x + a2 * v2.x + a3 * v3.x;
        acc.y += a0 * v0.y + a1 * v1.y + a2 * v2.y + a3 * v3.y;
        acc.z += a0 * v0.z + a1 * v1.z + a2 * v2.z + a3 * v3.z;
        acc.w += a0 * v0.w + a1 * v1.w + a2 * v2.w + a3 * v3.w;
    }
    for (; i < re; i++) {
        int2 cw = colw[i];
        float4 v = h4[((size_t)cw.x << LOG2C4) + lane];
        float w = __int_as_float(cw.y);
        acc.x += w * v.x; acc.y += w * v.y; acc.z += w * v.z; acc.w += w * v.w;
    }
    if (!ADDIN) {
        acc.x = fmaxf(acc.x, 0.0f); acc.y = fmaxf(acc.y, 0.0f);
        acc.z = fmaxf(acc.z, 0.0f); acc.w = fmaxf(acc.w, 0.0f);
    }
    out4[rowoff] = acc;
}

// ---------------- layer-1 GEMM: [outA|outB] = A @ [WA|WB], K=128, both mats ----------------
__global__ __launch_bounds__(256) void gemm1_k(const float* __restrict__ A,
                                               const float* __restrict__ WA,
                                               const float* __restrict__ WB,
                                               float* __restrict__ outA,
                                               float* __restrict__ outB, int n) {
    __shared__ float As[64 * 68];
    __shared__ float W1s[64 * 68];
    __shared__ float W2s[64 * 68];
    const int t = threadIdx.x;
    const int tj = t & 15;
    const int tn = t >> 4;
    const int n0 = blockIdx.x * 64;
    float acc[4][8] = {};

    for (int kc = 0; kc < 128; kc += 64) {
        if (kc) __syncthreads();
        {
            int idx = t;
#pragma unroll
            for (int r = 0; r < 4; r++, idx += 256) {
                int nl = idx >> 4, q = idx & 15;
                int node = n0 + nl; node = node < n ? node : n - 1;
                float4 a = ((const float4*)A)[(size_t)node * 32 + (kc >> 2) + q];
                *(float4*)&As[nl * 68 + q * 4] = a;
            }
        }
        {
            int idx = t;
#pragma unroll
            for (int r = 0; r < 4; r++, idx += 256) {
                int kl = idx >> 4, j4 = idx & 15;
                *(float4*)&W1s[kl * 68 + j4 * 4] = ((const float4*)WA)[(size_t)(kc + kl) * 16 + j4];
                *(float4*)&W2s[kl * 68 + j4 * 4] = ((const float4*)WB)[(size_t)(kc + kl) * 16 + j4];
            }
        }
        __syncthreads();

        const float* ap = &As[tn * 4 * 68];
        const float* w1p = &W1s[tj * 4];
        const float* w2p = &W2s[tj * 4];
#pragma unroll 2
        for (int k4 = 0; k4 < 16; k4++) {
            float4 a0 = *(const float4*)&ap[0 * 68 + k4 * 4];
            float4 a1 = *(const float4*)&ap[1 * 68 + k4 * 4];
            float4 a2 = *(const float4*)&ap[2 * 68 + k4 * 4];
            float4 a3 = *(const float4*)&ap[3 * 68 + k4 * 4];
#pragma unroll
            for (int kk = 0; kk < 4; kk++) {
                float4 w1 = *(const float4*)&w1p[(k4 * 4 + kk) * 68];
                float4 w2 = *(const float4*)&w2p[(k4 * 4 + kk) * 68];
                float av0 = kk == 0 ? a0.x : kk == 1 ? a0.y : kk == 2 ? a0.z : a0.w;
                float av1 = kk == 0 ? a1.x : kk == 1 ? a1.y : kk == 2 ? a1.z : a1.w;
                float av2 = kk == 0 ? a2.x : kk == 1 ? a2.y : kk == 2 ? a2.z : a2.w;
                float av3 = kk == 0 ? a3.x : kk == 1 ? a3.y : kk == 2 ? a3.z : a3.w;
#define FMA8(m, AV)                                                     \
                acc[m][0] += AV * w1.x; acc[m][1] += AV * w1.y;          \
                acc[m][2] += AV * w1.z; acc[m][3] += AV * w1.w;          \
                acc[m][4] += AV * w2.x; acc[m][5] += AV * w2.y;          \
                acc[m][6] += AV * w2.z; acc[m][7] += AV * w2.w;
                FMA8(0, av0)
                FMA8(1, av1)
                FMA8(2, av2)
                FMA8(3, av3)
#undef FMA8
            }
        }
    }

#pragma unroll
    for (int m = 0; m < 4; m++) {
        int node = n0 + tn * 4 + m;
        if (node < n) {
            *(float4*)&outA[(size_t)node * 64 + tj * 4] =
                make_float4(acc[m][0], acc[m][1], acc[m][2], acc[m][3]);
            *(float4*)&outB[(size_t)node * 64 + tj * 4] =
                make_float4(acc[m][4], acc[m][5], acc[m][6], acc[m][7]);
        }
    }
}

// ---------------- layer-2 GEMM: out = A @ [WA|WB], K=64, JW=32 ----------------
template<int K, int JW>
__global__ __launch_bounds__(256) void gemm_k(const float* __restrict__ A,
                                              const float* __restrict__ WA,
                                              const float* __restrict__ WB,
                                              float* __restrict__ out, int n) {
    __shared__ float As[64 * 68];
    __shared__ float Ws[64 * 68];
    const int t = threadIdx.x;
    const int tj = t & 15;
    const int tn = t >> 4;
    const int n0 = blockIdx.x * 64;
    float acc[4][4] = {};

    for (int kc = 0; kc < K; kc += 64) {
        if (kc) __syncthreads();
        {
            int idx = t;
#pragma unroll
            for (int r = 0; r < 4; r++, idx += 256) {
                int nl = idx >> 4, q = idx & 15;
                int node = n0 + nl; node = node < n ? node : n - 1;
                float4 a = ((const float4*)A)[(size_t)node * (K / 4) + (kc >> 2) + q];
                *(float4*)&As[nl * 68 + q * 4] = a;
            }
        }
        {
            int idx = t;
#pragma unroll
            for (int r = 0; r < 4; r++, idx += 256) {
                int kl = idx >> 4, j4 = idx & 15;
                const float* W = (j4 < 8) ? WA : WB;
                float4 w = ((const float4*)W)[(size_t)(kc + kl) * 8 + (j4 & 7)];
                *(float4*)&Ws[kl * 68 + j4 * 4] = w;
            }
        }
        __syncthreads();

        const float* ap = &As[tn * 4 * 68];
        const float* wp = &Ws[tj * 4];
#pragma unroll 4
        for (int k4 = 0; k4 < 16; k4++) {
            float4 a0 = *(const float4*)&ap[0 * 68 + k4 * 4];
            float4 a1 = *(const float4*)&ap[1 * 68 + k4 * 4];
            float4 a2 = *(const float4*)&ap[2 * 68 + k4 * 4];
            float4 a3 = *(const float4*)&ap[3 * 68 + k4 * 4];
            float4 w0 = *(const float4*)&wp[(k4 * 4 + 0) * 68];
            float4 w1 = *(const float4*)&wp[(k4 * 4 + 1) * 68];
            float4 w2 = *(const float4*)&wp[(k4 * 4 + 2) * 68];
            float4 w3 = *(const float4*)&wp[(k4 * 4 + 3) * 68];
#define FMA_ROW(m, AV)                                                   \
            acc[m][0] += AV.x * w0.x + AV.y * w1.x + AV.z * w2.x + AV.w * w3.x; \
            acc[m][1] += AV.x * w0.y + AV.y * w1.y + AV.z * w2.y + AV.w * w3.y; \
            acc[m][2] += AV.x * w0.z + AV.y * w1.z + AV.z * w2.z + AV.w * w3.z; \
            acc[m][3] += AV.x * w0.w + AV.y * w1.w + AV.z * w2.w + AV.w * w3.w;
            FMA_ROW(0, a0)
            FMA_ROW(1, a1)
            FMA_ROW(2, a2)
            FMA_ROW(3, a3)
#undef FMA_ROW
        }
    }

    int mat = tj >> 3;
    int jw = (tj & 7) * 4;
    float* ob = out + (size_t)mat * n * JW + jw;
#pragma unroll
    for (int m = 0; m < 4; m++) {
        int node = n0 + tn * 4 + m;
        if (node < n)
            *(float4*)&ob[(size_t)node * JW] =
                make_float4(acc[m][0], acc[m][1], acc[m][2], acc[m][3]);
    }
}

// ---------------- fused heads, 8 threads/node ----------------
// Block = 256 threads = 32 nodes. Per node: lane jq in [0,8) computes 4 of 32
// proj columns and 2 of 16 coord-hidden columns; t/tc exchanged via LDS.
// sh/st stride 36: per-wave scalar reads hit 8 distinct banks (8-lane bcast).
__global__ __launch_bounds__(256) void heads_k(const float* __restrict__ h2,
                                               const float* __restrict__ Wp1, const float* __restrict__ bp1,
                                               const float* __restrict__ Wp2, const float* __restrict__ bp2,
                                               const float* __restrict__ Wc1, const float* __restrict__ bc1,
                                               const float* __restrict__ Wc2, const float* __restrict__ bc2,
                                               float* __restrict__ coord, float* __restrict__ z, int n) {
    __shared__ float sWp1[32 * 32], sWp2[32 * 32], sWc1[32 * 16], sWc2[32];
    __shared__ float sbp1[32], sbp2[32], sbc1[16], sbc2[2];
    __shared__ float sh[32 * 36], st[32 * 36], stc[32 * 18];
    const int t = threadIdx.x;
    for (int i = t; i < 1024; i += 256) { sWp1[i] = Wp1[i]; sWp2[i] = Wp2[i]; }
    for (int i = t; i < 512; i += 256) sWc1[i] = Wc1[i];
    if (t < 32) { sWc2[t] = Wc2[t]; sbp1[t] = bp1[t]; sbp2[t] = bp2[t]; }
    if (t < 16) sbc1[t] = bc1[t];
    if (t < 2) sbc2[t] = bc2[t];

    const int n0 = blockIdx.x * 32;
    const int nl = t >> 3;       // node-local 0..31
    const int jq = t & 7;        // column quad 0..7
    const int node = n0 + nl;
    // stage h rows (one float4 per thread)
    {
        float4 v = make_float4(0.f, 0.f, 0.f, 0.f);
        if (node < n) v = *(const float4*)&h2[(size_t)node * 32 + jq * 4];
        *(float4*)&sh[nl * 36 + jq * 4] = v;
    }
    __syncthreads();

    // proj layer 1: t[jq*4..+3] = relu(bp1 + h . Wp1)
    float4 a = *(const float4*)&sbp1[jq * 4];
#pragma unroll
    for (int k = 0; k < 32; k++) {
        float hv = sh[nl * 36 + k];
        float4 w = *(const float4*)&sWp1[k * 32 + jq * 4];
        a.x += hv * w.x; a.y += hv * w.y; a.z += hv * w.z; a.w += hv * w.w;
    }
    a.x = fmaxf(a.x, 0.f); a.y = fmaxf(a.y, 0.f);
    a.z = fmaxf(a.z, 0.f); a.w = fmaxf(a.w, 0.f);
    *(float4*)&st[nl * 36 + jq * 4] = a;

    // coord layer 1: tc[jq*2, jq*2+1] = relu(bc1 + h . Wc1)
    float2 c = *(const float2*)&sbc1[jq * 2];
#pragma unroll
    for (int k = 0; k < 32; k++) {
        float hv = sh[nl * 36 + k];
        float2 w = *(const float2*)&sWc1[k * 16 + jq * 2];
        c.x += hv * w.x; c.y += hv * w.y;
    }
    c.x = fmaxf(c.x, 0.f); c.y = fmaxf(c.y, 0.f);
    *(float2*)&stc[nl * 18 + jq * 2] = c;
    __syncthreads();

    // proj layer 2: z[jq*4..+3] = bp2 + t . Wp2
    float4 zz = *(const float4*)&sbp2[jq * 4];
#pragma unroll
    for (int k = 0; k < 32; k++) {
        float tv = st[nl * 36 + k];
        float4 w = *(const float4*)&sWp2[k * 32 + jq * 4];
        zz.x += tv * w.x; zz.y += tv * w.y; zz.z += tv * w.z; zz.w += tv * w.w;
    }
    if (node < n) *(float4*)&z[(size_t)node * 32 + jq * 4] = zz;

    // coord layer 2: coord[jq] (jq<2) = bc2 + tc . Wc2
    if (jq < 2) {
        float s = sbc2[jq];
#pragma unroll
        for (int k = 0; k < 16; k++) s += stc[nl * 18 + k] * sWc2[k * 2 + jq];
        if (node < n) coord[(size_t)node * 2 + jq] = s;
    }
}

extern "C" void kernel_launch(void* const* d_in, const int* in_sizes, int n_in,
                              void* d_out, int out_size, void* d_ws, size_t ws_size,
                              hipStream_t stream) {
    const float* x    = (const float*)d_in[0];
    const int*   ei   = (const int*)d_in[1];
    const int*   src  = ei;
    const int*   dst  = ei + NE;
    const float* W1_1 = (const float*)d_in[2];
    const float* W1_2 = (const float*)d_in[3];
    const float* b1   = (const float*)d_in[4];
    const float* W2_1 = (const float*)d_in[5];
    const float* W2_2 = (const float*)d_in[6];
    const float* b2   = (const float*)d_in[7];
    const float* Wp1  = (const float*)d_in[8];
    const float* bp1  = (const float*)d_in[9];
    const float* Wp2  = (const float*)d_in[10];
    const float* bp2  = (const float*)d_in[11];
    const float* Wc1  = (const float*)d_in[12];
    const float* bc1  = (const float*)d_in[13];
    const float* Wc2  = (const float*)d_in[14];
    const float* bc2  = (const float*)d_in[15];

    // workspace layout (4-byte words; bufY offset padded to 16B alignment)
    float* ws    = (float*)d_ws;
    float* dinv  = ws;                              // NN
    int*   cnt   = (int*)(dinv + NN);               // NN
    int*   rows  = cnt + NN;                        // NN+2 (padded, keeps int2 8B-aligned)
    int*   bsum  = rows + NN + 2;                   // NBLK (+pad to even)
    int2*  colw  = (int2*)(bsum + NBLK + (NBLK & 1));  // NE int2
    float* bufY  = (float*)(colw + NE) + 2;         // +2 words -> 16B aligned; NN*128
    float* bufZ  = bufY + (size_t)NN * 128;         // NN*64

    float* y1 = bufY;                       // NN*64   (then reused as u)
    float* y2 = bufY + (size_t)NN * 64;     // NN*64   (then reused as h1)
    float* u  = y1;
    float* h1 = y2;
    float* z1 = bufZ;                       // NN*32   (then reused as u2)
    float* z2 = bufZ + (size_t)NN * 32;     // NN*32   (then reused as h2)
    float* u2 = z1;
    float* h2 = z2;

    float* coord = (float*)d_out;                   // NN*2
    float* z     = (float*)d_out + 2 * NN;          // NN*32

    // 1) CSR build + dinv (hierarchical scan; dinv folded into phase 1)
    zero_cnt_k<<<(NN + 255) / 256, 256, 0, stream>>>(cnt);
    hist_k<<<(NE + 255) / 256, 256, 0, stream>>>(dst, cnt);
    sum_blocks_k<<<NBLK, 256, 0, stream>>>(cnt, bsum, dinv);
    scan_blocks_k<<<1, 256, 0, stream>>>(bsum, rows);
    scan_final_k<<<NBLK, 256, 0, stream>>>(cnt, bsum, rows);
    scatter_k<<<(NE + 255) / 256, 256, 0, stream>>>(src, dst, rows, cnt, dinv, colw);

    // 2) [y1|y2] = x @ [W1_1|W1_2]   (K=128, both matrices in one pass)
    gemm1_k<<<(NN + 63) / 64, 256, 0, stream>>>(x, W1_1, W1_2, y1, y2, NN);
    // 3) u = y1 + P(y2)              (C=64)
    prop_k<4, true><<<(NN * 16 + 255) / 256, 256, 0, stream>>>(
        (const float4*)y2, (const float4*)y1, nullptr, (float4*)u, rows, colw, dinv);
    // 4) h1 = relu(P(u) + b1)        (C=64)
    prop_k<4, false><<<(NN * 16 + 255) / 256, 256, 0, stream>>>(
        (const float4*)u, nullptr, b1, (float4*)h1, rows, colw, dinv);
    // 5) [z1|z2] = h1 @ [W2_1|W2_2]  (K=64, one block spans both 32-wide mats)
    gemm_k<64, 32><<<(NN + 63) / 64, 256, 0, stream>>>(h1, W2_1, W2_2, bufZ, NN);
    // 6) u2 = z1 + P(z2)             (C=32)
    prop_k<3, true><<<(NN * 8 + 255) / 256, 256, 0, stream>>>(
        (const float4*)z2, (const float4*)z1, nullptr, (float4*)u2, rows, colw, dinv);
    // 7) h2 = relu(P(u2) + b2)       (C=32)
    prop_k<3, false><<<(NN * 8 + 255) / 256, 256, 0, stream>>>(
        (const float4*)u2, nullptr, b2, (float4*)h2, rows, colw, dinv);
    // 8) heads (8 threads/node)
    heads_k<<<(NN + 31) / 32, 256, 0, stream>>>(h2, Wp1, bp1, Wp2, bp2, Wc1, bc1, Wc2, bc2, coord, z, NN);
}